// Round 8
// baseline (129.915 us; speedup 1.0000x reference)
//
#include <hip/hip_runtime.h>

// MultiHeadAttentionForViTDiscriminator: B=4, C=1024, D=1024, H=16, DH=64
// R8: (1) X fp32->f16 conversion fused into GEMM staging (reg-staged fp32
//     operand with prefetch; W still pre-converted by small cvt_w) -- removes
//     the 12M-element X materialization pass. (2) attn den computed by a
//     ones-column MFMA (no per-element VALU adds, no epilogue shuffles).
//     attn otherwise = R7-proven structure.
// Workspace (48 MB):
//   [0,8M) W16 (Wq,Wk,Wv,Wp f16)  [8,16M) vTb  [16,24M) attnout
//   [32,40M) qb (pre-scaled by -2*C2)  [40,48M) kb
//   norms q2c2/k2c2 (2 x 256KB f32) live in d_out's head (dead before final GEMM).

typedef _Float16 f16;
typedef __attribute__((ext_vector_type(2))) _Float16 f16x2;
typedef __attribute__((ext_vector_type(8))) _Float16 f16x8;
typedef __attribute__((ext_vector_type(4))) float f32x4;

#define MFMA16(a, b, c) __builtin_amdgcn_mfma_f32_16x16x32_f16((a), (b), (c), 0, 0, 0)

constexpr double LOG2E = 1.4426950408889634;
constexpr double C2d = 0.015625 * LOG2E * LOG2E;  // (DH^-0.5 * log2e)^2

#if __has_builtin(__builtin_amdgcn_exp2f)
#define EXP2F(x) __builtin_amdgcn_exp2f(x)
#else
#define EXP2F(x) exp2f(x)
#endif
#if __has_builtin(__builtin_amdgcn_sqrtf)
#define SQRTF(x) __builtin_amdgcn_sqrtf(x)
#else
#define SQRTF(x) sqrtf(x)
#endif

// Async global->LDS, 16B per lane (dest = wave-uniform base + lane*16).
__device__ __forceinline__ void stage16(const f16* g, f16* lds_base_uniform) {
#if __has_builtin(__builtin_amdgcn_global_load_lds)
    __builtin_amdgcn_global_load_lds((const __attribute__((address_space(1))) void*)g,
                                     (__attribute__((address_space(3))) void*)lds_base_uniform,
                                     16, 0, 0);
#else
    const int lane = threadIdx.x & 63;
    *(f16x8*)(lds_base_uniform + lane * 8) = *(const f16x8*)g;
#endif
}

__device__ __forceinline__ f16x8 cvt8(float4 a, float4 b) {
    f16x8 o;
    o[0] = (f16)a.x; o[1] = (f16)a.y; o[2] = (f16)a.z; o[3] = (f16)a.w;
    o[4] = (f16)b.x; o[5] = (f16)b.y; o[6] = (f16)b.z; o[7] = (f16)b.w;
    return o;
}

// W conversion only (4 x 1M fp32 -> f16).
__global__ __launch_bounds__(256) void cvt_w4(const float* __restrict__ s0,
                                              const float* __restrict__ s1,
                                              const float* __restrict__ s2,
                                              const float* __restrict__ s3,
                                              f16* __restrict__ dst) {
    const float* src = (blockIdx.y == 0) ? s0 : (blockIdx.y == 1) ? s1 : (blockIdx.y == 2) ? s2 : s3;
    f16* d = dst + (size_t)blockIdx.y * (1u << 20);
    int i = (blockIdx.x * 256 + threadIdx.x) * 8;
    *(f16x8*)(d + i) = cvt8(*(const float4*)(src + i), *(const float4*)(src + i + 4));
}

// C[M,N] = (A[M,K] * B[N,K]^T) * osc.  BM=128 BN=64 BK=64; 4 waves, wave tile 32x64.
// MODE 0: qk fused (z=0 q / z=1 k). A = X fp32 (reg-staged+cvt), B = W16. NORMS.
// MODE 1: vT.  A = Wv16 (gload_lds), B = Xv fp32 (reg-staged+cvt).
// MODE 2: final. A,B f16 gload_lds; f32 out + bias.
template <int MODE>
__global__ __launch_bounds__(256, 2) void gemm(const float* __restrict__ Af0,
                                               const float* __restrict__ Af1,
                                               const f16* __restrict__ A16,
                                               const float* __restrict__ Bf,
                                               const f16* __restrict__ B16,
                                               f16* __restrict__ Co,
                                               float* __restrict__ Cf,
                                               const float* __restrict__ bias,
                                               float* __restrict__ nrm,
                                               float osc0, float osc1,
                                               float ns0, float ns1,
                                               int M, int N, int K) {
    constexpr bool A_F32 = (MODE == 0);
    constexpr bool B_F32 = (MODE == 1);
    constexpr bool NORMS = (MODE == 0);
    constexpr bool F32OUT = (MODE == 2);
    __shared__ __attribute__((aligned(16))) f16 As[128 * 64];
    __shared__ __attribute__((aligned(16))) f16 Bs[64 * 64];
    const int tid = threadIdx.x;
    const int lane = tid & 63;
    const int w = tid >> 6;
    const int l15 = lane & 15, l4 = lane >> 4;
    const int z = blockIdx.z;

    const float* Af = nullptr;
    const f16* A16p = A16;
    const f16* B16p = B16;
    if (A_F32) Af = z ? Af1 : Af0;
    if (MODE == 0) B16p = B16 + (size_t)z * (1u << 20);
    f16* Cop = Co + (A_F32 ? (size_t)z * (4u << 20) : 0);
    float* nrmp = nrm;
    if (NORMS) nrmp += (size_t)z * 65536;
    const float osc = z ? osc1 : osc0;
    const float nscale = z ? ns1 : ns0;
    const int wr = w * 32;
    // bijective XCD swizzle (nwg multiple of 8)
    const int nwg = gridDim.x * gridDim.y;
    const int f = blockIdx.y * gridDim.x + blockIdx.x;
    const int g = (f & 7) * (nwg >> 3) + (f >> 3);
    const int row0 = (g / gridDim.x) * 128;
    const int col0 = (g % gridDim.x) * 64;

    const int sr8 = lane >> 3;
    const int sc8 = (lane & 7) * 8;
    f32x4 acc[2][4] = {};

    // fp32-operand prefetch registers
    float4 xa[4], xb[4];  // A (4 x 8-row groups)
    float4 ya[2], yb[2];  // B (2 x 8-row groups)
#define LOADA(KT)                                                                              \
    _Pragma("unroll") for (int t = 0; t < 4; ++t) {                                            \
        const float* s_ = &Af[(size_t)(row0 + w * 32 + t * 8 + sr8) * K + (KT) + sc8];         \
        xa[t] = *(const float4*)s_;                                                            \
        xb[t] = *(const float4*)(s_ + 4);                                                      \
    }
#define LOADB(KT)                                                                              \
    _Pragma("unroll") for (int t = 0; t < 2; ++t) {                                            \
        const float* s_ = &Bf[(size_t)(col0 + w * 16 + t * 8 + sr8) * K + (KT) + sc8];         \
        ya[t] = *(const float4*)s_;                                                            \
        yb[t] = *(const float4*)(s_ + 4);                                                      \
    }

    if (A_F32) LOADA(0)
    if (B_F32) LOADB(0)

    for (int kt = 0; kt < K; kt += 64) {
        __syncthreads();
        if (A_F32) {
#pragma unroll
            for (int t = 0; t < 4; ++t)
                *(f16x8*)&As[(w * 32 + t * 8 + sr8) * 64 + sc8] = cvt8(xa[t], xb[t]);
        } else {
#pragma unroll
            for (int t = 0; t < 4; ++t)
                stage16(&A16p[(size_t)(row0 + w * 32 + t * 8 + sr8) * K + kt + sc8], &As[(w * 32 + t * 8) * 64]);
        }
        if (B_F32) {
#pragma unroll
            for (int t = 0; t < 2; ++t)
                *(f16x8*)&Bs[(w * 16 + t * 8 + sr8) * 64 + sc8] = cvt8(ya[t], yb[t]);
        } else {
#pragma unroll
            for (int t = 0; t < 2; ++t)
                stage16(&B16p[(size_t)(col0 + w * 16 + t * 8 + sr8) * K + kt + sc8], &Bs[(w * 16 + t * 8) * 64]);
        }
        __syncthreads();
        if (kt + 64 < K) {  // prefetch next fp32 tile; latency hides under MFMAs
            if (A_F32) LOADA(kt + 64)
            if (B_F32) LOADB(kt + 64)
        }
#pragma unroll
        for (int ks = 0; ks < 2; ++ks) {
            f16x8 af[2], bf[4];
#pragma unroll
            for (int m = 0; m < 2; ++m)
                af[m] = *(const f16x8*)&As[(wr + m * 16 + l15) * 64 + ks * 32 + l4 * 8];
#pragma unroll
            for (int n = 0; n < 4; ++n)
                bf[n] = *(const f16x8*)&Bs[(n * 16 + l15) * 64 + ks * 32 + l4 * 8];
#pragma unroll
            for (int m = 0; m < 2; ++m)
#pragma unroll
                for (int n = 0; n < 4; ++n) acc[m][n] = MFMA16(af[m], bf[n], acc[m][n]);
        }
    }

    if (NORMS) {
        const int h = col0 >> 6;
#pragma unroll
        for (int m = 0; m < 2; ++m)
#pragma unroll
            for (int r = 0; r < 4; ++r) {
                float s = 0.f;
#pragma unroll
                for (int n = 0; n < 4; ++n) {
                    float v = (float)(f16)(acc[m][n][r] * osc);
                    s += v * v;
                }
                s += __shfl_xor(s, 1);
                s += __shfl_xor(s, 2);
                s += __shfl_xor(s, 4);
                s += __shfl_xor(s, 8);
                if (l15 == 0) {
                    int row = row0 + wr + m * 16 + l4 * 4 + r;
                    nrmp[(size_t)((row >> 10) * 16 + h) * 1024 + (row & 1023)] = s * nscale;
                }
            }
    }

#pragma unroll
    for (int m = 0; m < 2; ++m)
#pragma unroll
        for (int n = 0; n < 4; ++n)
#pragma unroll
            for (int r = 0; r < 4; ++r) {
                int rr = row0 + wr + m * 16 + l4 * 4 + r;
                int cc = col0 + n * 16 + l15;
                if (F32OUT)
                    Cf[(size_t)rr * N + cc] = acc[m][n][r] + bias[cc];
                else
                    Cop[(size_t)rr * N + cc] = (f16)(acc[m][n][r] * osc);
            }
#undef LOADA
#undef LOADB
}

// Distance attention. grid (8,64): 128 q-rows/block, 4 waves x 32 rows.
// Swapped QK (A=K,B=Q) + permuted K slots => in-register P; no Ps LDS.
// den via ones-column MFMA: lands in accv row layout, no epilogue shuffles.
__global__ __launch_bounds__(256, 2) void attn(const f16* __restrict__ qs,
                                               const f16* __restrict__ kb,
                                               const f16* __restrict__ vT,
                                               const float* __restrict__ q2c2,
                                               const float* __restrict__ k2c2,
                                               f16* __restrict__ out) {
    __shared__ __attribute__((aligned(16))) f16 Ks[128 * 64];  // permuted slots + XOR swizzle
    __shared__ __attribute__((aligned(16))) f16 Vs[64 * 128];  // XOR-swizzled
    __shared__ float k2tile[128];                              // linear (keyed by true k)
    const int tid = threadIdx.x;
    const int lane = tid & 63;
    const int w = tid >> 6;
    const int l15 = lane & 15, l4 = lane >> 4;
    // XCD remap: 8 bh per XCD -> K/V slices L2-resident
    const int fid = blockIdx.y * 8 + blockIdx.x;
    const int qt = (fid >> 3) & 7;
    const int bh = (fid & 7) * 8 + (fid >> 6);
    const int b = bh >> 4, h = bh & 15;
    const int wq = w * 32;
    const int hcol = h * 64;
    const int qrow0 = b * 1024 + qt * 128;
    const f16* vTh = vT + (size_t)hcol * 4096 + b * 1024;  // vT[d=1024][tok=4096]

    const int sr = tid >> 3, sc0 = (tid & 7) * 8;   // K staging (keys sr+i*32)
    const int vr = tid >> 4, vc0 = (tid & 15) * 8;  // V staging (rows vr+j*16)
    const int vsw = (vr & 7) << 3;
    const int fsw = (l15 & 7) << 3;                 // fragment-read swizzle (slot-row&7 = l15&7)

    // Q frags as B-operand (rows wq+m*16+l15), pre-scaled by -2*C2
    f16x8 bq[2][2];
#pragma unroll
    for (int m = 0; m < 2; ++m)
#pragma unroll
        for (int ks = 0; ks < 2; ++ks)
            bq[m][ks] = *(const f16x8*)&qs[(size_t)(qrow0 + wq + m * 16 + l15) * 1024 + hcol + ks * 32 + l4 * 8];
    // q2*C2 at lane-local q (col index l15)
    float q2m[2];
#pragma unroll
    for (int m = 0; m < 2; ++m) q2m[m] = q2c2[(size_t)bh * 1024 + qt * 128 + wq + m * 16 + l15];

    f32x4 accv[2][4] = {};
    f32x4 dacc[2] = {};
    const f16 one = (f16)1.f;
    const f16x8 ones8 = {one, one, one, one, one, one, one, one};

    f16x8 kreg[4], vreg[4];
    float k2reg = 0.f;
#define ISSUE_LOADS(KT)                                                                                      \
    {                                                                                                        \
        _Pragma("unroll") for (int i = 0; i < 4; ++i)                                                        \
            kreg[i] = *(const f16x8*)&kb[(size_t)(b * 1024 + (KT) * 128 + sr + i * 32) * 1024 + hcol + sc0]; \
        _Pragma("unroll") for (int j = 0; j < 4; ++j)                                                        \
            vreg[j] = *(const f16x8*)&vTh[(size_t)(vr + j * 16) * 4096 + (KT) * 128 + vc0];                  \
        k2reg = (tid < 128) ? k2c2[(size_t)bh * 1024 + (KT) * 128 + tid] : 0.f;                              \
    }

    ISSUE_LOADS(0)

    for (int kt = 0; kt < 8; ++kt) {
        __syncthreads();  // prev-tile readers done
        // K staging with slot permutation: key kap -> slot s so that QK D-rows
        // deliver PV A-frag k-order.
#pragma unroll
        for (int i = 0; i < 4; ++i) {
            const int kap = sr + i * 32;
            const int s = ((kap >> 5) & 3) * 32 + ((kap >> 2) & 1) * 16 + ((kap >> 3) & 3) * 4 + (kap & 3);
            *(f16x8*)&Ks[s * 64 + (sc0 ^ ((s & 7) << 3))] = kreg[i];
        }
#pragma unroll
        for (int j = 0; j < 4; ++j) *(f16x8*)&Vs[(vr + j * 16) * 128 + (vc0 ^ vsw)] = vreg[j];
        if (tid < 128) k2tile[tid] = k2reg;
        __syncthreads();
        if (kt < 7) ISSUE_LOADS(kt + 1)  // prefetch hides under compute

#pragma unroll
        for (int kk = 0; kk < 4; ++kk) {
            // QK for windows n=2kk, 2kk+1; assemble PV A-frag dwords in-register
            unsigned um[2][4];
#pragma unroll
            for (int half = 0; half < 2; ++half) {
                const int n = kk * 2 + half;
                f16x8 kf0 = *(const f16x8*)&Ks[(n * 16 + l15) * 64 + ((l4 * 8) ^ fsw)];
                f16x8 kf1 = *(const f16x8*)&Ks[(n * 16 + l15) * 64 + ((32 + l4 * 8) ^ fsw)];
                // true keys at this lane's D-rows: kk*32 + l4*8 + half*4 + r
                f32x4 k2q = *(const f32x4*)&k2tile[kk * 32 + l4 * 8 + half * 4];
#pragma unroll
                for (int m = 0; m < 2; ++m) {
                    f32x4 c0;
#pragma unroll
                    for (int r = 0; r < 4; ++r) c0[r] = q2m[m] + k2q[r];
                    f32x4 st = MFMA16(kf0, bq[m][0], c0);
                    st = MFMA16(kf1, bq[m][1], st);
                    float p0 = EXP2F(SQRTF(fmaxf(st[0], 0.f)));
                    float p1 = EXP2F(SQRTF(fmaxf(st[1], 0.f)));
                    float p2 = EXP2F(SQRTF(fmaxf(st[2], 0.f)));
                    float p3 = EXP2F(SQRTF(fmaxf(st[3], 0.f)));
                    f16x2 lo = {(f16)p0, (f16)p1};
                    f16x2 hi = {(f16)p2, (f16)p3};
                    um[m][half * 2] = __builtin_bit_cast(unsigned, lo);
                    um[m][half * 2 + 1] = __builtin_bit_cast(unsigned, hi);
                }
            }
            f16x8 ap[2];
#pragma unroll
            for (int m = 0; m < 2; ++m) {
                uint4 u = {um[m][0], um[m][1], um[m][2], um[m][3]};
                ap[m] = __builtin_bit_cast(f16x8, u);
            }
            // den += P * 1 (ones-column): D[q][*] = row-sum partial, accv row layout
#pragma unroll
            for (int m = 0; m < 2; ++m) dacc[m] = MFMA16(ap[m], ones8, dacc[m]);
            // PV for this kk (B-operand: V^T rows = d = n2*16+l15)
#pragma unroll
            for (int n2 = 0; n2 < 4; ++n2) {
                f16x8 bv = *(const f16x8*)&Vs[(n2 * 16 + l15) * 128 + ((kk * 32 + l4 * 8) ^ fsw)];
#pragma unroll
                for (int m = 0; m < 2; ++m) accv[m][n2] = MFMA16(ap[m], bv, accv[m][n2]);
            }
        }
    }

    // dacc[m][r] = full den for q-row (wq + m*16 + l4*4 + r) -- same row map as accv
#pragma unroll
    for (int m = 0; m < 2; ++m)
#pragma unroll
        for (int r = 0; r < 4; ++r) {
            const float rd = 1.0f / dacc[m][r];
#pragma unroll
            for (int n2 = 0; n2 < 4; ++n2)
                out[(size_t)(qrow0 + wq + m * 16 + l4 * 4 + r) * 1024 + hcol + n2 * 16 + l15] =
                    (f16)(accv[m][n2][r] * rd);
        }
}

extern "C" void kernel_launch(void* const* d_in, const int* in_sizes, int n_in,
                              void* d_out, int out_size, void* d_ws, size_t ws_size,
                              hipStream_t stream) {
    const float* Xq = (const float*)d_in[0];
    const float* Xk = (const float*)d_in[1];
    const float* Xv = (const float*)d_in[2];
    const float* Wq = (const float*)d_in[3];
    const float* Wk = (const float*)d_in[4];
    const float* Wv = (const float*)d_in[5];
    const float* Wp = (const float*)d_in[6];
    const float* bp = (const float*)d_in[7];
    float* out = (float*)d_out;

    char* ws = (char*)d_ws;
    f16* W16 = (f16*)(ws);                      // 4M f16
    f16* vTb = (f16*)(ws + (8ull << 20));
    f16* attnout = (f16*)(ws + (16ull << 20));
    f16* qb = (f16*)(ws + (32ull << 20));       // qk out base (z-stride 4M f16)
    f16* kb = (f16*)(ws + (40ull << 20));
    // norms scratch in d_out head; written each launch before use, overwritten by final GEMM
    float* q2c2 = out;
    float* k2c2 = out + 65536;

    const float qsc = (float)(-2.0 * C2d);
    const float ns_q = (float)(1.0 / (4.0 * C2d));  // (q*-2C2)^2 * ns_q = C2*q^2
    const float ns_k = (float)C2d;

    cvt_w4<<<dim3(512, 4), 256, 0, stream>>>(Wq, Wk, Wv, Wp, W16);

    // fused q+k projection (z=0: q with -2*C2 prescale, z=1: k), A = fp32 X staged+cvt
    gemm<0><<<dim3(16, 32, 2), 256, 0, stream>>>(
        Xq, Xk, nullptr, nullptr, W16, qb, nullptr, nullptr, q2c2,
        qsc, 1.0f, ns_q, ns_k, 4096, 1024, 1024);

    // vT = Wv16 * Xv^T : [1024 d][4096 tok], B = fp32 Xv staged+cvt
    gemm<1><<<dim3(64, 8), 256, 0, stream>>>(
        nullptr, nullptr, W16 + 2 * (1u << 20), Xv, nullptr, vTb, nullptr, nullptr, nullptr,
        1.0f, 1.0f, 0.f, 0.f, 1024, 4096, 1024);

    attn<<<dim3(8, 64), 256, 0, stream>>>(qb, kb, vTb, q2c2, k2c2, attnout);

    gemm<2><<<dim3(16, 32), 256, 0, stream>>>(
        nullptr, nullptr, attnout, nullptr, W16 + 3 * (1u << 20), nullptr, out, bp, nullptr,
        1.0f, 1.0f, 0.f, 0.f, 4096, 1024, 1024);
}

// Round 9
// 118.925 us; speedup vs baseline: 1.0924x; 1.0924x over previous
//
#include <hip/hip_runtime.h>

// MultiHeadAttentionForViTDiscriminator: B=4, C=1024, D=1024, H=16, DH=64
// R9: GEMM rebuilt: (1) fp32 X staged directly via global_load_lds into f32 LDS,
//     cvt after ds_read (RTE) -- removes X materialization pass without R8's
//     reg-staging serialization (VGPR56 spill/sink). (2) All LDS tiles XOR-
//     swizzled via pre-swizzled global source (m173 pattern) -- kills the 9.4M
//     frag-read bank conflicts. (3) Inner loop on mfma_f32_32x32x16_f16
//     (k-pairing cancels for LDS-LDS operands; D-layout per verified formula).
//     attn = R8-proven version, untouched.
// Workspace (48 MB):
//   [0,8M) W16 (Wq,Wk,Wv,Wp f16)  [8,16M) vTb  [16,24M) attnout
//   [32,40M) qb (pre-scaled by -2*C2)  [40,48M) kb
//   norms q2c2/k2c2 (2 x 256KB f32) live in d_out's head (dead before final GEMM).

typedef _Float16 f16;
typedef __attribute__((ext_vector_type(2))) _Float16 f16x2;
typedef __attribute__((ext_vector_type(8))) _Float16 f16x8;
typedef __attribute__((ext_vector_type(4))) float f32x4;
typedef __attribute__((ext_vector_type(16))) float f32x16;

#define MFMA16(a, b, c) __builtin_amdgcn_mfma_f32_16x16x32_f16((a), (b), (c), 0, 0, 0)
#define MFMA32(a, b, c) __builtin_amdgcn_mfma_f32_32x32x16_f16((a), (b), (c), 0, 0, 0)

constexpr double LOG2E = 1.4426950408889634;
constexpr double C2d = 0.015625 * LOG2E * LOG2E;  // (DH^-0.5 * log2e)^2

#if __has_builtin(__builtin_amdgcn_exp2f)
#define EXP2F(x) __builtin_amdgcn_exp2f(x)
#else
#define EXP2F(x) exp2f(x)
#endif
#if __has_builtin(__builtin_amdgcn_sqrtf)
#define SQRTF(x) __builtin_amdgcn_sqrtf(x)
#else
#define SQRTF(x) sqrtf(x)
#endif

// Async global->LDS, 16B per lane (dest = wave-uniform base + lane*16).
__device__ __forceinline__ void stage16(const void* g, void* lds_base_uniform) {
#if __has_builtin(__builtin_amdgcn_global_load_lds)
    __builtin_amdgcn_global_load_lds((const __attribute__((address_space(1))) void*)g,
                                     (__attribute__((address_space(3))) void*)lds_base_uniform,
                                     16, 0, 0);
#else
    const int lane = threadIdx.x & 63;
    *(f16x8*)((f16*)lds_base_uniform + lane * 8) = *(const f16x8*)g;
#endif
}

__device__ __forceinline__ f16x8 cvt8v(f32x4 a, f32x4 b) {
    f16x8 o;
    o[0] = (f16)a[0]; o[1] = (f16)a[1]; o[2] = (f16)a[2]; o[3] = (f16)a[3];
    o[4] = (f16)b[0]; o[5] = (f16)b[1]; o[6] = (f16)b[2]; o[7] = (f16)b[3];
    return o;
}

// W conversion only (4 x 1M fp32 -> f16).
__global__ __launch_bounds__(256) void cvt_w4(const float* __restrict__ s0,
                                              const float* __restrict__ s1,
                                              const float* __restrict__ s2,
                                              const float* __restrict__ s3,
                                              f16* __restrict__ dst) {
    const float* src = (blockIdx.y == 0) ? s0 : (blockIdx.y == 1) ? s1 : (blockIdx.y == 2) ? s2 : s3;
    f16* d = dst + (size_t)blockIdx.y * (1u << 20);
    int i = (blockIdx.x * 256 + threadIdx.x) * 8;
    f32x4 a = *(const f32x4*)(src + i);
    f32x4 b = *(const f32x4*)(src + i + 4);
    *(f16x8*)(d + i) = cvt8v(a, b);
}

// C[M,N] = (A[M,K] * B[N,K]^T) * osc.  BM=128 BN=64 BK=64; 4 waves, wave tile 32x64.
// MFMA 32x32x16; all LDS tiles XOR-swizzled (pre-swizzled gload_lds source).
// MODE 0: qk fused (z=0 q / z=1 k). A = X fp32 (f32 LDS, cvt-on-read), B = W16. NORMS.
// MODE 1: vT.  A = Wv16, B = Xv fp32 (f32 LDS, cvt-on-read).
// MODE 2: final. A,B f16; f32 out + bias.
template <int MODE>
__global__ __launch_bounds__(256, 2) void gemm(const float* __restrict__ Af0,
                                               const float* __restrict__ Af1,
                                               const f16* __restrict__ A16,
                                               const float* __restrict__ Bf,
                                               const f16* __restrict__ B16,
                                               f16* __restrict__ Co,
                                               float* __restrict__ Cf,
                                               const float* __restrict__ bias,
                                               float* __restrict__ nrm,
                                               float osc0, float osc1,
                                               float ns0, float ns1,
                                               int M, int N, int K) {
    constexpr bool AF32 = (MODE == 0);
    constexpr bool BF32 = (MODE == 1);
    constexpr bool NORMS = (MODE == 0);
    constexpr bool F32OUT = (MODE == 2);
    constexpr int BOFF = AF32 ? 32768 : 16384;  // byte offset of B tile
    constexpr int SMEM = BOFF + (BF32 ? 16384 : 8192);
    __shared__ __attribute__((aligned(16))) char smem[SMEM];
    float* AsF = (float*)smem;            // MODE0: 128x64 f32
    f16* As16 = (f16*)smem;               // else: 128x64 f16
    float* BsF = (float*)(smem + BOFF);   // MODE1: 64x64 f32
    f16* Bs16 = (f16*)(smem + BOFF);      // else: 64x64 f16

    const int tid = threadIdx.x;
    const int lane = tid & 63;
    const int w = tid >> 6;
    const int l31 = lane & 31, l5 = lane >> 5, l7 = lane & 7;
    const int z = blockIdx.z;
    const float* Af = AF32 ? (z ? Af1 : Af0) : nullptr;
    const f16* A16p = A16;
    const f16* B16p = (MODE == 0) ? B16 + (size_t)z * (1u << 20) : B16;
    f16* Cop = AF32 ? Co + (size_t)z * (4u << 20) : Co;
    float* nrmp = NORMS ? nrm + (size_t)z * 65536 : nullptr;
    const float osc = z ? osc1 : osc0;
    const float nscale = z ? ns1 : ns0;
    const int wr = w * 32;
    // bijective XCD swizzle (nwg multiple of 8)
    const int nwg = gridDim.x * gridDim.y;
    const int f = blockIdx.y * gridDim.x + blockIdx.x;
    const int g = (f & 7) * (nwg >> 3) + (f >> 3);
    const int row0 = (g / gridDim.x) * 128;
    const int col0 = (g % gridDim.x) * 64;

    f32x16 acc[2] = {};

    for (int kt = 0; kt < K; kt += 64) {
        __syncthreads();
        // ---- stage A (swizzled source: granule g -> g ^ (row&7)) ----
        if (AF32) {
#pragma unroll
            for (int t = 0; t < 8; ++t) {
                const int rb = w * 32 + t * 4;
                const int rr = rb + (lane >> 4);
                const int gs = (lane & 15) ^ (rr & 7);
                stage16(&Af[(size_t)(row0 + rr) * K + kt + gs * 4], &AsF[rb * 64]);
            }
        } else {
#pragma unroll
            for (int t = 0; t < 4; ++t) {
                const int rb = w * 32 + t * 8;
                const int rr = rb + (lane >> 3);
                const int gs = l7 ^ (rr & 7);
                stage16(&A16p[(size_t)(row0 + rr) * K + kt + gs * 8], &As16[rb * 64]);
            }
        }
        // ---- stage B ----
        if (BF32) {
#pragma unroll
            for (int t = 0; t < 4; ++t) {
                const int rb = w * 16 + t * 4;
                const int rr = rb + (lane >> 4);
                const int gs = (lane & 15) ^ (rr & 7);
                stage16(&Bf[(size_t)(col0 + rr) * K + kt + gs * 4], &BsF[rb * 64]);
            }
        } else {
#pragma unroll
            for (int t = 0; t < 2; ++t) {
                const int rb = w * 16 + t * 8;
                const int rr = rb + (lane >> 3);
                const int gs = l7 ^ (rr & 7);
                stage16(&B16p[(size_t)(col0 + rr) * K + kt + gs * 8], &Bs16[rb * 64]);
            }
        }
        __syncthreads();
#pragma unroll
        for (int ks = 0; ks < 4; ++ks) {  // K=64 -> 4 x K16
            f16x8 af;
            if (AF32) {
                const int g0 = ks * 4 + l5 * 2;
                f32x4 a0 = *(const f32x4*)&AsF[(wr + l31) * 64 + ((g0 ^ l7) * 4)];
                f32x4 a1 = *(const f32x4*)&AsF[(wr + l31) * 64 + (((g0 + 1) ^ l7) * 4)];
                af = cvt8v(a0, a1);
            } else {
                af = *(const f16x8*)&As16[(wr + l31) * 64 + (((ks * 2 + l5) ^ l7) * 8)];
            }
#pragma unroll
            for (int n2 = 0; n2 < 2; ++n2) {
                f16x8 bf;
                if (BF32) {
                    const int g0 = ks * 4 + l5 * 2;
                    f32x4 b0 = *(const f32x4*)&BsF[(n2 * 32 + l31) * 64 + ((g0 ^ l7) * 4)];
                    f32x4 b1 = *(const f32x4*)&BsF[(n2 * 32 + l31) * 64 + (((g0 + 1) ^ l7) * 4)];
                    bf = cvt8v(b0, b1);
                } else {
                    bf = *(const f16x8*)&Bs16[(n2 * 32 + l31) * 64 + (((ks * 2 + l5) ^ l7) * 8)];
                }
                acc[n2] = MFMA32(af, bf, acc[n2]);
            }
        }
    }

    // D layout (verified): col = l31 (+n2*32), row_local = (j&3) + 8*(j>>2) + 4*l5
#pragma unroll
    for (int j = 0; j < 16; ++j) {
        const int rr = row0 + wr + (j & 3) + 8 * (j >> 2) + 4 * l5;
        if (NORMS) {
            float v0 = (float)(f16)(acc[0][j] * osc);
            float v1 = (float)(f16)(acc[1][j] * osc);
            float s = v0 * v0 + v1 * v1;
            s += __shfl_xor(s, 1);
            s += __shfl_xor(s, 2);
            s += __shfl_xor(s, 4);
            s += __shfl_xor(s, 8);
            s += __shfl_xor(s, 16);
            if (l31 == 0)
                nrmp[(size_t)((rr >> 10) * 16 + (col0 >> 6)) * 1024 + (rr & 1023)] = s * nscale;
        }
        if (F32OUT) {
            Cf[(size_t)rr * N + col0 + l31] = acc[0][j] + bias[col0 + l31];
            Cf[(size_t)rr * N + col0 + 32 + l31] = acc[1][j] + bias[col0 + 32 + l31];
        } else {
            Cop[(size_t)rr * N + col0 + l31] = (f16)(acc[0][j] * osc);
            Cop[(size_t)rr * N + col0 + 32 + l31] = (f16)(acc[1][j] * osc);
        }
    }
}

// Distance attention (R8-proven). grid (8,64): 128 q-rows/block, 4 waves x 32 rows.
// Swapped QK (A=K,B=Q) + permuted K slots => in-register P; den via ones-MFMA.
__global__ __launch_bounds__(256, 2) void attn(const f16* __restrict__ qs,
                                               const f16* __restrict__ kb,
                                               const f16* __restrict__ vT,
                                               const float* __restrict__ q2c2,
                                               const float* __restrict__ k2c2,
                                               f16* __restrict__ out) {
    __shared__ __attribute__((aligned(16))) f16 Ks[128 * 64];  // permuted slots + XOR swizzle
    __shared__ __attribute__((aligned(16))) f16 Vs[64 * 128];  // XOR-swizzled
    __shared__ float k2tile[128];                              // linear (keyed by true k)
    const int tid = threadIdx.x;
    const int lane = tid & 63;
    const int w = tid >> 6;
    const int l15 = lane & 15, l4 = lane >> 4;
    const int fid = blockIdx.y * 8 + blockIdx.x;
    const int qt = (fid >> 3) & 7;
    const int bh = (fid & 7) * 8 + (fid >> 6);
    const int b = bh >> 4, h = bh & 15;
    const int wq = w * 32;
    const int hcol = h * 64;
    const int qrow0 = b * 1024 + qt * 128;
    const f16* vTh = vT + (size_t)hcol * 4096 + b * 1024;  // vT[d=1024][tok=4096]

    const int sr = tid >> 3, sc0 = (tid & 7) * 8;   // K staging (keys sr+i*32)
    const int vr = tid >> 4, vc0 = (tid & 15) * 8;  // V staging (rows vr+j*16)
    const int vsw = (vr & 7) << 3;
    const int fsw = (l15 & 7) << 3;                 // fragment-read swizzle

    f16x8 bq[2][2];
#pragma unroll
    for (int m = 0; m < 2; ++m)
#pragma unroll
        for (int ks = 0; ks < 2; ++ks)
            bq[m][ks] = *(const f16x8*)&qs[(size_t)(qrow0 + wq + m * 16 + l15) * 1024 + hcol + ks * 32 + l4 * 8];
    float q2m[2];
#pragma unroll
    for (int m = 0; m < 2; ++m) q2m[m] = q2c2[(size_t)bh * 1024 + qt * 128 + wq + m * 16 + l15];

    f32x4 accv[2][4] = {};
    f32x4 dacc[2] = {};
    const f16 one = (f16)1.f;
    const f16x8 ones8 = {one, one, one, one, one, one, one, one};

    f16x8 kreg[4], vreg[4];
    float k2reg = 0.f;
#define ISSUE_LOADS(KT)                                                                                      \
    {                                                                                                        \
        _Pragma("unroll") for (int i = 0; i < 4; ++i)                                                        \
            kreg[i] = *(const f16x8*)&kb[(size_t)(b * 1024 + (KT) * 128 + sr + i * 32) * 1024 + hcol + sc0]; \
        _Pragma("unroll") for (int j = 0; j < 4; ++j)                                                        \
            vreg[j] = *(const f16x8*)&vTh[(size_t)(vr + j * 16) * 4096 + (KT) * 128 + vc0];                  \
        k2reg = (tid < 128) ? k2c2[(size_t)bh * 1024 + (KT) * 128 + tid] : 0.f;                              \
    }

    ISSUE_LOADS(0)

    for (int kt = 0; kt < 8; ++kt) {
        __syncthreads();
#pragma unroll
        for (int i = 0; i < 4; ++i) {
            const int kap = sr + i * 32;
            const int s = ((kap >> 5) & 3) * 32 + ((kap >> 2) & 1) * 16 + ((kap >> 3) & 3) * 4 + (kap & 3);
            *(f16x8*)&Ks[s * 64 + (sc0 ^ ((s & 7) << 3))] = kreg[i];
        }
#pragma unroll
        for (int j = 0; j < 4; ++j) *(f16x8*)&Vs[(vr + j * 16) * 128 + (vc0 ^ vsw)] = vreg[j];
        if (tid < 128) k2tile[tid] = k2reg;
        __syncthreads();
        if (kt < 7) ISSUE_LOADS(kt + 1)

#pragma unroll
        for (int kk = 0; kk < 4; ++kk) {
            unsigned um[2][4];
#pragma unroll
            for (int half = 0; half < 2; ++half) {
                const int n = kk * 2 + half;
                f16x8 kf0 = *(const f16x8*)&Ks[(n * 16 + l15) * 64 + ((l4 * 8) ^ fsw)];
                f16x8 kf1 = *(const f16x8*)&Ks[(n * 16 + l15) * 64 + ((32 + l4 * 8) ^ fsw)];
                f32x4 k2q = *(const f32x4*)&k2tile[kk * 32 + l4 * 8 + half * 4];
#pragma unroll
                for (int m = 0; m < 2; ++m) {
                    f32x4 c0;
#pragma unroll
                    for (int r = 0; r < 4; ++r) c0[r] = q2m[m] + k2q[r];
                    f32x4 st = MFMA16(kf0, bq[m][0], c0);
                    st = MFMA16(kf1, bq[m][1], st);
                    float p0 = EXP2F(SQRTF(fmaxf(st[0], 0.f)));
                    float p1 = EXP2F(SQRTF(fmaxf(st[1], 0.f)));
                    float p2 = EXP2F(SQRTF(fmaxf(st[2], 0.f)));
                    float p3 = EXP2F(SQRTF(fmaxf(st[3], 0.f)));
                    f16x2 lo = {(f16)p0, (f16)p1};
                    f16x2 hi = {(f16)p2, (f16)p3};
                    um[m][half * 2] = __builtin_bit_cast(unsigned, lo);
                    um[m][half * 2 + 1] = __builtin_bit_cast(unsigned, hi);
                }
            }
            f16x8 ap[2];
#pragma unroll
            for (int m = 0; m < 2; ++m) {
                uint4 u = {um[m][0], um[m][1], um[m][2], um[m][3]};
                ap[m] = __builtin_bit_cast(f16x8, u);
            }
#pragma unroll
            for (int m = 0; m < 2; ++m) dacc[m] = MFMA16(ap[m], ones8, dacc[m]);
#pragma unroll
            for (int n2 = 0; n2 < 4; ++n2) {
                f16x8 bv = *(const f16x8*)&Vs[(n2 * 16 + l15) * 128 + ((kk * 32 + l4 * 8) ^ fsw)];
#pragma unroll
                for (int m = 0; m < 2; ++m) accv[m][n2] = MFMA16(ap[m], bv, accv[m][n2]);
            }
        }
    }

#pragma unroll
    for (int m = 0; m < 2; ++m)
#pragma unroll
        for (int r = 0; r < 4; ++r) {
            const float rd = 1.0f / dacc[m][r];
#pragma unroll
            for (int n2 = 0; n2 < 4; ++n2)
                out[(size_t)(qrow0 + wq + m * 16 + l4 * 4 + r) * 1024 + hcol + n2 * 16 + l15] =
                    (f16)(accv[m][n2][r] * rd);
        }
}

extern "C" void kernel_launch(void* const* d_in, const int* in_sizes, int n_in,
                              void* d_out, int out_size, void* d_ws, size_t ws_size,
                              hipStream_t stream) {
    const float* Xq = (const float*)d_in[0];
    const float* Xk = (const float*)d_in[1];
    const float* Xv = (const float*)d_in[2];
    const float* Wq = (const float*)d_in[3];
    const float* Wk = (const float*)d_in[4];
    const float* Wv = (const float*)d_in[5];
    const float* Wp = (const float*)d_in[6];
    const float* bp = (const float*)d_in[7];
    float* out = (float*)d_out;

    char* ws = (char*)d_ws;
    f16* W16 = (f16*)(ws);                      // 4M f16
    f16* vTb = (f16*)(ws + (8ull << 20));
    f16* attnout = (f16*)(ws + (16ull << 20));
    f16* qb = (f16*)(ws + (32ull << 20));       // qk out base (z-stride 4M f16)
    f16* kb = (f16*)(ws + (40ull << 20));
    // norms scratch in d_out head; written each launch before use, overwritten by final GEMM
    float* q2c2 = out;
    float* k2c2 = out + 65536;

    const float qsc = (float)(-2.0 * C2d);
    const float ns_q = (float)(1.0 / (4.0 * C2d));  // (q*-2C2)^2 * ns_q = C2*q^2
    const float ns_k = (float)C2d;

    cvt_w4<<<dim3(512, 4), 256, 0, stream>>>(Wq, Wk, Wv, Wp, W16);

    // fused q+k projection (z=0: q with -2*C2 prescale, z=1: k); A = fp32 X in LDS
    gemm<0><<<dim3(16, 32, 2), 256, 0, stream>>>(
        Xq, Xk, nullptr, nullptr, W16, qb, nullptr, nullptr, q2c2,
        qsc, 1.0f, ns_q, ns_k, 4096, 1024, 1024);

    // vT = Wv16 * Xv^T : [1024 d][4096 tok]; B = fp32 Xv in LDS
    gemm<1><<<dim3(64, 8), 256, 0, stream>>>(
        nullptr, nullptr, W16 + 2 * (1u << 20), Xv, nullptr, vTb, nullptr, nullptr, nullptr,
        1.0f, 1.0f, 0.f, 0.f, 1024, 4096, 1024);

    attn<<<dim3(8, 64), 256, 0, stream>>>(qb, kb, vTb, q2c2, k2c2, attnout);

    gemm<2><<<dim3(16, 32), 256, 0, stream>>>(
        nullptr, nullptr, attnout, nullptr, W16 + 3 * (1u << 20), nullptr, out, bp, nullptr,
        1.0f, 1.0f, 0.f, 0.f, 4096, 1024, 1024);
}